// Round 4
// baseline (138.374 us; speedup 1.0000x reference)
//
#include <hip/hip_runtime.h>
#include <hip/hip_bf16.h>
#include <stdint.h>

// Problem constants
#define BATCH 16
#define IN_CH 64
#define HIN 56
#define WIN_ 56
#define HO 54
#define WO 54
#define P_PER_B (HO*WO)        // 2916
#define P_PAD 2944             // 23 * 128
#define OUT_CH 256
#define KDIM 576               // 64*3*3
#define NPIX (HIN*WIN_)        // 3136

typedef __attribute__((ext_vector_type(8))) short short8;
typedef __attribute__((ext_vector_type(4))) float f32x4;

__device__ __forceinline__ unsigned short f2bf(float f) {
    unsigned int u = __float_as_uint(f);
    unsigned int r = (u + 0x7fffu + ((u >> 16) & 1u)) >> 16;   // RNE
    return (unsigned short)r;
}

// ---------------- prep kernels ----------------

// One wave per output channel: bf16-convert weight row REORDERED to k' = tap*64 + c
// (tap = kh*3+kw); compute ||w_o||^2 in fp32.
__global__ void prep_weight(const float* __restrict__ w, short* __restrict__ wbf,
                            float* __restrict__ c2) {
    int o = blockIdx.x;
    int lane = threadIdx.x;           // 0..63
    float s = 0.f;
    #pragma unroll
    for (int j = 0; j < 9; ++j) {     // 576 = 9*64
        int k = j * 64 + lane;        // original k = c*9 + tap
        int c = k / 9, tap = k % 9;
        float v = w[o * KDIM + k];
        s += v * v;
        ((unsigned short*)wbf)[o * KDIM + tap * 64 + c] = f2bf(v);
    }
    #pragma unroll
    for (int off = 32; off > 0; off >>= 1) s += __shfl_down(s, off);
    if (lane == 0) c2[o] = s;
}

// NCHW fp32 -> NHWC bf16 transpose (64 pix x 64 ch per block) + fused per-pixel
// channel square-sum s[b, pix].
__global__ __launch_bounds__(256) void transpose_kernel(
    const float* __restrict__ x, short* __restrict__ xT, float* __restrict__ s) {
    __shared__ short lds[64 * 65];
    __shared__ float red[256];
    const int b    = blockIdx.x / 49;
    const int pix0 = (blockIdx.x % 49) * 64;
    const int tid  = threadIdx.x;
    const int quarter = tid >> 6;
    const int pix  = tid & 63;
    const float* xb = x + (size_t)b * IN_CH * NPIX + pix0 + pix;
    float acc = 0.f;
    #pragma unroll
    for (int it = 0; it < 16; ++it) {
        int c = quarter * 16 + it;
        float v = xb[c * NPIX];               // wave reads 256B contiguous
        acc += v * v;
        lds[pix * 65 + c] = (short)f2bf(v);
    }
    red[tid] = acc;
    __syncthreads();
    const int cs = tid & 63;
    short* xTb = xT + ((size_t)b * NPIX + pix0) * 64;
    #pragma unroll
    for (int it = 0; it < 16; ++it) {
        int pixs = quarter * 16 + it;
        xTb[(size_t)pixs * 64 + cs] = lds[pixs * 65 + cs];  // wave writes 128B contiguous
    }
    if (tid < 64)
        s[b * NPIX + pix0 + tid] = red[tid] + red[64 + tid] + red[128 + tid] + red[192 + tid];
}

// w2[b*P_PAD + p] = 3x3 window sum of s  (= ||win_p||^2, fp32)
__global__ void w2_kernel(const float* __restrict__ s, float* __restrict__ w2) {
    int t = blockIdx.x * 256 + threadIdx.x;
    if (t >= BATCH * P_PER_B) return;
    int b = t / P_PER_B, p = t % P_PER_B;
    int oh = p / WO, ow = p % WO;
    const float* sp = s + b * NPIX + oh * WIN_ + ow;
    float acc = 0.f;
    #pragma unroll
    for (int kh = 0; kh < 3; ++kh)
        #pragma unroll
        for (int kw = 0; kw < 3; ++kw)
            acc += sp[kh * WIN_ + kw];
    w2[b * P_PAD + p] = acc;
}

// ---------------- fused im2col GEMM + RBF epilogue ----------------
// BARRIER-FREE, LDS-FREE register pipeline. Each wave owns a 64x64 tile of
// C[m][n] = sum_k A[m][k'] * wbf[n][k'] (k' = tap*64 + c). A and B fragments
// are loaded DIRECTLY global->VGPR (16B/lane dwordx4, all cache-resident),
// double-buffered across taps in registers; compiler emits fine-grained
// vmcnt(N) waits (AITER-style) since there is no __syncthreads at all.
// Batch index sits in blockIdx.x's low bits -> blockIdx%8 XCD round-robin
// keeps each XCD's xT slice (2 batches = 0.8 MB) + wbf (288 KB) L2-resident.

__global__ __launch_bounds__(256, 2) void gemm_rbf(
    const short* __restrict__ xT, const short* __restrict__ wbf,
    const float* __restrict__ w2, const float* __restrict__ c2,
    float* __restrict__ out) {
    constexpr int dtab[9] = {0, 1, 2, 56, 57, 58, 112, 113, 114};  // kh*56+kw

    const int bx = blockIdx.x;
    const int b  = bx & 15;                    // batch (low bits -> XCD-local)
    const int p0 = (bx >> 4) * 128;            // M-tile origin (0..22)
    const int n0 = blockIdx.y * 128;

    const int tid  = threadIdx.x;
    const int wave = tid >> 6;
    const int lane = tid & 63;
    const int r16  = lane & 15;
    const int quad = lane >> 4;
    const int wm = (wave >> 1) * 64;
    const int wn = (wave & 1) * 64;

    const short* xTb = xT + (size_t)b * NPIX * 64;

    // per-lane fragment base pointers (A: 4 m-frags, B: 4 n-frags)
    const short* aB[4];
    const short* bB[4];
    #pragma unroll
    for (int ms = 0; ms < 4; ++ms) {
        int p = p0 + wm + ms * 16 + r16;
        if (p > P_PER_B - 1) p = P_PER_B - 1;  // clamp pad rows (epilogue skips)
        int oh = p / WO, ow = p - oh * WO;
        aB[ms] = xTb + (size_t)(oh * WIN_ + ow) * 64 + quad * 8;
    }
    #pragma unroll
    for (int ns = 0; ns < 4; ++ns)
        bB[ns] = wbf + (size_t)(n0 + wn + ns * 16 + r16) * KDIM + quad * 8;

    f32x4 acc[4][4];
    #pragma unroll
    for (int i = 0; i < 4; ++i)
        #pragma unroll
        for (int j = 0; j < 4; ++j)
            acc[i][j] = (f32x4){0.f, 0.f, 0.f, 0.f};

    short8 Af[2][4][2], Bf[2][4][2];
    // preload tap 0
    #pragma unroll
    for (int ms = 0; ms < 4; ++ms)
        #pragma unroll
        for (int ks = 0; ks < 2; ++ks)
            Af[0][ms][ks] = *(const short8*)(aB[ms] + dtab[0] * 64 + ks * 32);
    #pragma unroll
    for (int ns = 0; ns < 4; ++ns)
        #pragma unroll
        for (int ks = 0; ks < 2; ++ks)
            Bf[0][ns][ks] = *(const short8*)(bB[ns] + ks * 32);

    #pragma unroll
    for (int t = 0; t < 9; ++t) {
        const int cur = t & 1, nxt = cur ^ 1;
        if (t < 8) {                            // prefetch tap t+1 into other regs
            #pragma unroll
            for (int ms = 0; ms < 4; ++ms)
                #pragma unroll
                for (int ks = 0; ks < 2; ++ks)
                    Af[nxt][ms][ks] = *(const short8*)(aB[ms] + dtab[t + 1] * 64 + ks * 32);
            #pragma unroll
            for (int ns = 0; ns < 4; ++ns)
                #pragma unroll
                for (int ks = 0; ks < 2; ++ks)
                    Bf[nxt][ns][ks] = *(const short8*)(bB[ns] + (t + 1) * 64 + ks * 32);
        }
        #pragma unroll
        for (int ks = 0; ks < 2; ++ks)
            #pragma unroll
            for (int ms = 0; ms < 4; ++ms)
                #pragma unroll
                for (int ns = 0; ns < 4; ++ns)
                    acc[ms][ns] = __builtin_amdgcn_mfma_f32_16x16x32_bf16(
                        Af[cur][ms][ks], Bf[cur][ns][ks], acc[ms][ns], 0, 0, 0);
    }

    // Epilogue: D layout n = lane&15, m = quad*4 + reg -> 4 regs are 4 consecutive
    // positions p for one channel o => float4 store.
    #pragma unroll
    for (int ms = 0; ms < 4; ++ms) {
        int pl = wm + ms * 16 + quad * 4;
        int p  = p0 + pl;
        if (p >= P_PER_B) continue;
        f32x4 w2v = *(const f32x4*)(w2 + b * P_PAD + p);   // pad region valid mem
        bool full = (p + 3 < P_PER_B);
        #pragma unroll
        for (int ns = 0; ns < 4; ++ns) {
            int o = n0 + wn + ns * 16 + r16;
            float c2o = c2[o];
            f32x4 v;
            #pragma unroll
            for (int r = 0; r < 4; ++r) {
                float d2 = w2v[r] + c2o - 2.0f * acc[ms][ns][r];
                d2 = fmaxf(d2, 1e-12f);
                v[r] = __expf(-0.125f * d2);
            }
            float* outp = out + ((size_t)(b * OUT_CH + o)) * P_PER_B + p;
            if (full) {
                *(f32x4*)outp = v;
            } else {
                #pragma unroll
                for (int r = 0; r < 4; ++r)
                    if (p + r < P_PER_B) outp[r] = v[r];
            }
        }
    }
}

// ---------------- launch ----------------

extern "C" void kernel_launch(void* const* d_in, const int* in_sizes, int n_in,
                              void* d_out, int out_size, void* d_ws, size_t ws_size,
                              hipStream_t stream) {
    const float* x = (const float*)d_in[0];    // [16,64,56,56]
    const float* w = (const float*)d_in[1];    // [256,576]
    float* out = (float*)d_out;                // [16,256,54,54]

    char* ws = (char*)d_ws;
    const size_t wbf_bytes = (size_t)OUT_CH * KDIM * 2;            // 294,912
    const size_t c2_bytes  = 1024;                                 // OUT_CH*4
    const size_t w2_bytes  = (size_t)BATCH * P_PAD * 4;            // 188,416
    const size_t s_bytes   = (size_t)BATCH * NPIX * 4;             // 200,704
    short* wbf = (short*)ws;
    float* c2  = (float*)(ws + wbf_bytes);
    float* w2  = (float*)(ws + wbf_bytes + c2_bytes);
    float* s   = (float*)(ws + wbf_bytes + c2_bytes + w2_bytes);
    short* xT  = (short*)(ws + wbf_bytes + c2_bytes + w2_bytes + s_bytes);  // 6.4 MB

    hipLaunchKernelGGL(prep_weight, dim3(OUT_CH), dim3(64), 0, stream, w, wbf, c2);
    hipLaunchKernelGGL(transpose_kernel, dim3(16 * 49), dim3(256), 0, stream, x, xT, s);
    hipLaunchKernelGGL(w2_kernel, dim3((BATCH * P_PER_B + 255) / 256), dim3(256), 0, stream, s, w2);
    // blockIdx.x = mtile*16 + batch  (batch in low bits for XCD L2 locality)
    hipLaunchKernelGGL(gemm_rbf, dim3(23 * BATCH, OUT_CH / 128), dim3(256), 0, stream,
                       xT, wbf, w2, c2, out);
}

// Round 5
// 107.533 us; speedup vs baseline: 1.2868x; 1.2868x over previous
//
#include <hip/hip_runtime.h>
#include <hip/hip_bf16.h>
#include <stdint.h>

// Problem constants
#define BATCH 16
#define IN_CH 64
#define HIN 56
#define WIN_ 56
#define HO 54
#define WO 54
#define P_PER_B (HO*WO)        // 2916
#define P_PAD 2944
#define OUT_CH 256
#define KDIM 576               // 64*3*3
#define NPIX (HIN*WIN_)        // 3136

typedef __attribute__((ext_vector_type(8))) short short8;
typedef __attribute__((ext_vector_type(4))) float f32x4;

__device__ __forceinline__ unsigned short f2bf(float f) {
    unsigned int u = __float_as_uint(f);
    unsigned int r = (u + 0x7fffu + ((u >> 16) & 1u)) >> 16;   // RNE
    return (unsigned short)r;
}

// ---------------- prep kernels ----------------

// One wave per output channel o: bf16-convert + repack weights into FRAGMENT-LINEAR
// layout wbf2[n/16][tap][ks][quad][n%16][8ch] so a B-frag load in the GEMM is
// base + lane*16B (perfectly coalesced global->VGPR, no LDS). Also ||w_o||^2 fp32.
__global__ void prep_weight(const float* __restrict__ w, short* __restrict__ wbf2,
                            float* __restrict__ c2) {
    int o = blockIdx.x;
    int lane = threadIdx.x;           // 0..63
    int ng = o >> 4, nl = o & 15;
    float s = 0.f;
    #pragma unroll
    for (int j = 0; j < 9; ++j) {     // 576 = 9*64
        int k = j * 64 + lane;        // original k = c*9 + tap
        int c = k / 9, tap = k % 9;
        float v = w[o * KDIM + k];
        s += v * v;
        int ks = c >> 5, qd = (c >> 3) & 3, cl = c & 7;
        ((unsigned short*)wbf2)[((((ng * 9 + tap) * 2 + ks) * 4 + qd) * 16 + nl) * 8 + cl]
            = f2bf(v);
    }
    #pragma unroll
    for (int off = 32; off > 0; off >>= 1) s += __shfl_down(s, off);
    if (lane == 0) c2[o] = s;
}

// NCHW fp32 -> NHWC bf16 transpose (64 pix x 64 ch per block) + fused per-pixel
// channel square-sum s[b, pix].
__global__ __launch_bounds__(256) void transpose_kernel(
    const float* __restrict__ x, short* __restrict__ xT, float* __restrict__ s) {
    __shared__ short lds[64 * 65];
    __shared__ float red[256];
    const int b    = blockIdx.x / 49;
    const int pix0 = (blockIdx.x % 49) * 64;
    const int tid  = threadIdx.x;
    const int quarter = tid >> 6;
    const int pix  = tid & 63;
    const float* xb = x + (size_t)b * IN_CH * NPIX + pix0 + pix;
    float acc = 0.f;
    #pragma unroll
    for (int it = 0; it < 16; ++it) {
        int c = quarter * 16 + it;
        float v = xb[c * NPIX];               // wave reads 256B contiguous
        acc += v * v;
        lds[pix * 65 + c] = (short)f2bf(v);
    }
    red[tid] = acc;
    __syncthreads();
    const int cs = tid & 63;
    short* xTb = xT + ((size_t)b * NPIX + pix0) * 64;
    #pragma unroll
    for (int it = 0; it < 16; ++it) {
        int pixs = quarter * 16 + it;
        xTb[(size_t)pixs * 64 + cs] = lds[pixs * 65 + cs];  // wave writes 128B contiguous
    }
    if (tid < 64)
        s[b * NPIX + pix0 + tid] = red[tid] + red[64 + tid] + red[128 + tid] + red[192 + tid];
}

// w2[b*P_PAD + p] = 3x3 window sum of s  (= ||win_p||^2, fp32)
__global__ void w2_kernel(const float* __restrict__ s, float* __restrict__ w2) {
    int t = blockIdx.x * 256 + threadIdx.x;
    if (t >= BATCH * P_PER_B) return;
    int b = t / P_PER_B, p = t % P_PER_B;
    int oh = p / WO, ow = p % WO;
    const float* sp = s + b * NPIX + oh * WIN_ + ow;
    float acc = 0.f;
    #pragma unroll
    for (int kh = 0; kh < 3; ++kh)
        #pragma unroll
        for (int kw = 0; kw < 3; ++kw)
            acc += sp[kh * WIN_ + kw];
    w2[b * P_PAD + p] = acc;
}

// ---------------- fused im2col GEMM + RBF epilogue ----------------
// ONE WAVE per 64x64 output tile; NO __syncthreads anywhere.
//  - A: the wave's whole 9-tap window is a contiguous 184-row slice of xT
//    (23 KB); staged ONCE into wave-private LDS (coalesced 1KB/instr loads,
//    144B padded rows -> 2-way banks = free). K-loop reads frags via
//    ds_read_b128 only.
//  - B: direct global->VGPR from fragment-linear wbf2 (base + lane*16B,
//    fully coalesced, L2-resident), double-buffered across taps; compiler
//    tracks vmcnt via register deps.
// Occupancy: 2944 single-wave blocks, 26.5KB LDS -> ~6 waves/CU, no barrier
// coupling. Batch in blockIdx.x low bits -> XCD L2 locality.

__global__ __launch_bounds__(64, 2) void gemm_rbf(
    const short* __restrict__ xT, const short* __restrict__ wbf2,
    const float* __restrict__ w2, const float* __restrict__ c2,
    float* __restrict__ out) {
    constexpr int dtab[9] = {0, 1, 2, 56, 57, 58, 112, 113, 114};  // kh*56+kw
    __shared__ __align__(16) short ldsA[184 * 72];   // 144 B per pixel row

    const int bx = blockIdx.x;
    const int b  = bx & 15;                    // batch (low bits -> XCD-local)
    const int p0 = (bx >> 4) * 64;             // m-tile origin (0..45)
    const int n0 = blockIdx.y * 64;

    const int lane = threadIdx.x;              // 0..63
    const int r16  = lane & 15;
    const int quad = lane >> 4;

    // ---- stage the A-window once (no barrier: wave-private) ----
    const int q0 = p0 + 2 * (p0 / WO);         // first pixel row of window
    const short* g = xT + ((size_t)b * NPIX + q0) * 64;
    #pragma unroll
    for (int i = 0; i < 23; ++i) {             // 184 rows * 8 chunks / 64 lanes
        int c = i * 64 + lane;
        short8 v = *(const short8*)(g + c * 8);
        int q = c >> 3, ch = c & 7;
        *(short8*)(ldsA + q * 72 + ch * 8) = v;
    }

    // per-lane relative LDS row for each m-frag
    int qr[4];
    #pragma unroll
    for (int ms = 0; ms < 4; ++ms) {
        int p = p0 + ms * 16 + r16;
        if (p > P_PER_B - 1) p = P_PER_B - 1;  // pad lanes (epilogue skips)
        qr[ms] = (p + 2 * (p / WO)) - q0;
    }

    // B fragment pointers: one frag = 64 lanes * 16B contiguous
    const short* bb = wbf2 + (size_t)(n0 >> 4) * 9 * 2 * 512 + lane * 8;

    f32x4 acc[4][4];
    #pragma unroll
    for (int i = 0; i < 4; ++i)
        #pragma unroll
        for (int j = 0; j < 4; ++j)
            acc[i][j] = (f32x4){0.f, 0.f, 0.f, 0.f};

    short8 Bf[2][4][2];
    #pragma unroll
    for (int ns = 0; ns < 4; ++ns)
        #pragma unroll
        for (int ks = 0; ks < 2; ++ks)
            Bf[0][ns][ks] = *(const short8*)(bb + (ns * 9 * 2 + ks) * 512);

    #pragma unroll
    for (int t = 0; t < 9; ++t) {
        const int cur = t & 1, nxt = cur ^ 1;
        if (t < 8) {                            // prefetch B for tap t+1
            #pragma unroll
            for (int ns = 0; ns < 4; ++ns)
                #pragma unroll
                for (int ks = 0; ks < 2; ++ks)
                    Bf[nxt][ns][ks] =
                        *(const short8*)(bb + ((ns * 9 + t + 1) * 2 + ks) * 512);
        }
        short8 af[4][2];
        #pragma unroll
        for (int ms = 0; ms < 4; ++ms) {
            int rowb = (qr[ms] + dtab[t]) * 72;
            #pragma unroll
            for (int ks = 0; ks < 2; ++ks)
                af[ms][ks] = *(const short8*)(ldsA + rowb + (ks * 4 + quad) * 8);
        }
        #pragma unroll
        for (int ks = 0; ks < 2; ++ks)
            #pragma unroll
            for (int ms = 0; ms < 4; ++ms)
                #pragma unroll
                for (int ns = 0; ns < 4; ++ns)
                    acc[ms][ns] = __builtin_amdgcn_mfma_f32_16x16x32_bf16(
                        af[ms][ks], Bf[cur][ns][ks], acc[ms][ns], 0, 0, 0);
    }

    // Epilogue: D layout n = lane&15, m = quad*4 + reg -> 4 regs = 4 consecutive
    // positions p for one channel o => float4 store.
    #pragma unroll
    for (int ms = 0; ms < 4; ++ms) {
        int p = p0 + ms * 16 + quad * 4;
        if (p >= P_PER_B) continue;
        f32x4 w2v = *(const f32x4*)(w2 + b * P_PAD + p);   // pad region valid mem
        bool full = (p + 3 < P_PER_B);
        #pragma unroll
        for (int ns = 0; ns < 4; ++ns) {
            int o = n0 + ns * 16 + r16;
            float c2o = c2[o];
            f32x4 v;
            #pragma unroll
            for (int r = 0; r < 4; ++r) {
                float d2 = w2v[r] + c2o - 2.0f * acc[ms][ns][r];
                d2 = fmaxf(d2, 1e-12f);
                v[r] = __expf(-0.125f * d2);
            }
            float* outp = out + ((size_t)(b * OUT_CH + o)) * P_PER_B + p;
            if (full) {
                *(f32x4*)outp = v;
            } else {
                #pragma unroll
                for (int r = 0; r < 4; ++r)
                    if (p + r < P_PER_B) outp[r] = v[r];
            }
        }
    }
}

// ---------------- launch ----------------

extern "C" void kernel_launch(void* const* d_in, const int* in_sizes, int n_in,
                              void* d_out, int out_size, void* d_ws, size_t ws_size,
                              hipStream_t stream) {
    const float* x = (const float*)d_in[0];    // [16,64,56,56]
    const float* w = (const float*)d_in[1];    // [256,576]
    float* out = (float*)d_out;                // [16,256,54,54]

    char* ws = (char*)d_ws;
    const size_t wbf_bytes = (size_t)OUT_CH * KDIM * 2;            // 294,912
    const size_t c2_bytes  = 1024;
    const size_t w2_bytes  = (size_t)BATCH * P_PAD * 4;            // 188,416
    const size_t s_bytes   = (size_t)BATCH * NPIX * 4;             // 200,704
    short* wbf2 = (short*)ws;
    float* c2  = (float*)(ws + wbf_bytes);
    float* w2  = (float*)(ws + wbf_bytes + c2_bytes);
    float* s   = (float*)(ws + wbf_bytes + c2_bytes + w2_bytes);
    short* xT  = (short*)(ws + wbf_bytes + c2_bytes + w2_bytes + s_bytes);  // 6.4 MB
    // note: gemm may read up to ~4.5 KB past xT's end (window over-read of
    // clamped last tiles) — still well inside d_ws.

    hipLaunchKernelGGL(prep_weight, dim3(OUT_CH), dim3(64), 0, stream, w, wbf2, c2);
    hipLaunchKernelGGL(transpose_kernel, dim3(16 * 49), dim3(256), 0, stream, x, xT, s);
    hipLaunchKernelGGL(w2_kernel, dim3((BATCH * P_PER_B + 255) / 256), dim3(256), 0, stream, s, w2);
    // blockIdx.x = mtile*16 + batch (batch in low bits for XCD L2 locality)
    hipLaunchKernelGGL(gemm_rbf, dim3(46 * BATCH, OUT_CH / 64), dim3(64), 0, stream,
                       xT, wbf2, w2, c2, out);
}